// Round 2
// baseline (7235.403 us; speedup 1.0000x reference)
//
#include <hip/hip_runtime.h>
#include <math.h>

// DCGRU encoder — fused per-(layer,batch) persistent blocks.
// B=16 T=32 N=128 D=H=128, K=2 (M=3), L=2, 1 support.
//
// Previous version: 256 blocks x 4 grid-barrier phases per stage (132 grid
// barriers); all intermediates round-tripped through global across blocks.
// Counters: MfmaUtil 1.25%, VALUBusy 3.8%, HBM 5.7% -> latency/sync bound.
//
// This version: 32 persistent blocks (layer = bid>>4, b = bid&15), 1024 thr,
// one block per CU (128 KB LDS). The whole per-(layer,b) timestep runs inside
// the block:
//   Hs   : h state, f32 [128][128], LDS, swizzled (f ^ (n&31))
//   W1/W2: two 32KB bf16 [128][128] work tiles (catT / D1T / rhT / A-chunks),
//          XOR-swizzled (c ^ ((r&7)<<3)) for conflict-free ds_read_b128
//   D1/D2: block-private global bf16 [128][256] (L2-resident), column-swizzled
// Phases per stage: P1 diffusion of [x|h] (2 halves) | P2 gates GEMM |
// P3 diffusion of rh half only (x-half of cat2 == x-half of cat, reuse D1/D2
// x-columns!) | P4 candidate GEMM + GRU update.
// Layers pipelined one stage apart; only cross-block dep is layer0->layer1
// via seqs => ONE grid barrier per stage (33 total, 32 blocks).

typedef __attribute__((ext_vector_type(8))) short bf16x8;
typedef __attribute__((ext_vector_type(4))) float f32x4;

namespace {
constexpr int GD = 32, NTHR = 1024;
}

__device__ __forceinline__ unsigned short f2bf(float x) {
  unsigned u = __float_as_uint(x);
  u += 0x7fff + ((u >> 16) & 1);  // RNE
  return (unsigned short)(u >> 16);
}
__device__ __forceinline__ float bf2f(unsigned hw) {
  return __uint_as_float(hw << 16);
}
__device__ __forceinline__ unsigned pk2(float a, float b) {
  return (unsigned)f2bf(a) | ((unsigned)f2bf(b) << 16);
}
// swizzled halfword index into a [128][128] bf16 LDS tile (row stride 256B)
__device__ __forceinline__ int BIdx(int r, int c) {
  return (r << 7) + (c ^ ((r & 7) << 3));
}
// swizzled word index into the [128][128] f32 h tile (column reads spread)
__device__ __forceinline__ int HsIdx(int n, int f) {
  return (n << 7) + (f ^ (n & 31));
}

// sense-reversing grid barrier (verified across XCDs in earlier session)
__device__ __forceinline__ void grid_barrier(unsigned* bar) {
  __syncthreads();
  if (threadIdx.x == 0) {
    unsigned* cnt = bar;
    unsigned* gen = bar + 32;
    unsigned g = __hip_atomic_load(gen, __ATOMIC_RELAXED, __HIP_MEMORY_SCOPE_AGENT);
    unsigned a = __hip_atomic_fetch_add(cnt, 1u, __ATOMIC_ACQ_REL, __HIP_MEMORY_SCOPE_AGENT);
    if (a == (unsigned)(GD - 1)) {
      __hip_atomic_store(cnt, 0u, __ATOMIC_RELAXED, __HIP_MEMORY_SCOPE_AGENT);
      __hip_atomic_fetch_add(gen, 1u, __ATOMIC_ACQ_REL, __HIP_MEMORY_SCOPE_AGENT);
    } else {
      while (__hip_atomic_load(gen, __ATOMIC_ACQUIRE, __HIP_MEMORY_SCOPE_AGENT) == g) {
        __builtin_amdgcn_s_sleep(1);
      }
    }
  }
  __syncthreads();
}

// One diffusion hop over a 128-feature half (all 16 waves, tile 32m x 32f):
//   acc = S @ Bt            (Bt: transposed tile in LDS, rows=feature, cols=n)
//   if Ct: acc = 2*acc - Ct (Chebyshev step; Ct rows=feature, cols=m)
//   if Ot: Ot[f][m] = acc   (transposed copy for the next hop)
//   Dg[m][dbase+f] = acc    (row-major column-swizzled global, for A-staging)
__device__ __forceinline__ void diff_half(
    const unsigned short* __restrict__ Sb, const unsigned short* Bt,
    const unsigned short* Ct, unsigned short* Ot,
    unsigned short* __restrict__ Dg, int dbase,
    int w, int lane, int quad, int l16) {
  const int mtg = w >> 2, ftg = w & 3;
  f32x4 acc[2][2];
#pragma unroll
  for (int mi = 0; mi < 2; ++mi)
#pragma unroll
    for (int fi = 0; fi < 2; ++fi) acc[mi][fi] = (f32x4){0.f, 0.f, 0.f, 0.f};
#pragma unroll
  for (int ks = 0; ks < 4; ++ks) {
    bf16x8 a[2], bb[2];
#pragma unroll
    for (int mi = 0; mi < 2; ++mi)
      a[mi] = *(const bf16x8*)(Sb + (((mtg * 2 + mi) * 4 + ks) * 64 + lane) * 8);
#pragma unroll
    for (int fi = 0; fi < 2; ++fi)
      bb[fi] = *(const bf16x8*)(Bt + BIdx((ftg * 2 + fi) * 16 + l16, ks * 32 + quad * 8));
#pragma unroll
    for (int mi = 0; mi < 2; ++mi)
#pragma unroll
      for (int fi = 0; fi < 2; ++fi)
        acc[mi][fi] =
            __builtin_amdgcn_mfma_f32_16x16x32_bf16(a[mi], bb[fi], acc[mi][fi], 0, 0, 0);
  }
#pragma unroll
  for (int mi = 0; mi < 2; ++mi)
#pragma unroll
    for (int fi = 0; fi < 2; ++fi) {
      const int f = (ftg * 2 + fi) * 16 + l16;
      const int m0 = (mtg * 2 + mi) * 16 + quad * 4;
      float v0 = acc[mi][fi][0], v1 = acc[mi][fi][1];
      float v2 = acc[mi][fi][2], v3 = acc[mi][fi][3];
      if (Ct) {
        const uint2 cv = *(const uint2*)(Ct + BIdx(f, m0));
        v0 = 2.f * v0 - bf2f(cv.x & 0xffffu);
        v1 = 2.f * v1 - bf2f(cv.x >> 16);
        v2 = 2.f * v2 - bf2f(cv.y & 0xffffu);
        v3 = 2.f * v3 - bf2f(cv.y >> 16);
      }
      if (Ot) *(uint2*)(Ot + BIdx(f, m0)) = make_uint2(pk2(v0, v1), pk2(v2, v3));
      const int d = dbase + f;
      Dg[(m0 + 0) * 256 + (d ^ (((m0 + 0) & 7) << 3))] = f2bf(v0);
      Dg[(m0 + 1) * 256 + (d ^ (((m0 + 1) & 7) << 3))] = f2bf(v1);
      Dg[(m0 + 2) * 256 + (d ^ (((m0 + 2) & 7) << 3))] = f2bf(v2);
      Dg[(m0 + 3) * 256 + (d ^ (((m0 + 3) & 7) << 3))] = f2bf(v3);
    }
}

// Stage A-chunk c (k in [c*128,(c+1)*128)) of xc = [x|h(or rh)|D1|D2] into W1.
// c==1: from Hs (gates path) or from rhT in W2 (candidate path).
// c>=2: D1g/D2g storage is already column-swizzled, chunk offset is bit7 of
// the column index and the swizzle only touches bits 3..5, so the copy is a
// plain linear memcpy and BIdx reads on W1 retrieve the right elements.
__device__ __forceinline__ void stage_chunk(
    int c, bool gates, int tid, const float* __restrict__ xsrc,
    const float* Hsp, const unsigned short* W2p, unsigned short* W1p,
    const unsigned short* __restrict__ D1b, const unsigned short* __restrict__ D2b) {
  if (c == 0) {
    const int row = tid >> 3, cb = (tid & 7) << 4;
#pragma unroll
    for (int j = 0; j < 4; ++j) {
      const float4 v = *(const float4*)(xsrc + row * 128 + cb + j * 4);
      *(uint2*)(W1p + BIdx(row, cb + j * 4)) = make_uint2(pk2(v.x, v.y), pk2(v.z, v.w));
    }
  } else if (c == 1) {
    if (gates) {
      const int row = tid >> 3, cb = (tid & 7) << 4;
#pragma unroll
      for (int j = 0; j < 8; ++j) {
        const float v0 = Hsp[HsIdx(row, cb + 2 * j)];
        const float v1 = Hsp[HsIdx(row, cb + 2 * j + 1)];
        *(unsigned*)(W1p + BIdx(row, cb + 2 * j)) = pk2(v0, v1);
      }
    } else {
      // transpose-read rhT (W2) -> row-major chunk
      const int m = tid & 127, db = (tid >> 7) << 4;
      unsigned short tmp[16];
#pragma unroll
      for (int j = 0; j < 16; ++j) tmp[j] = W2p[BIdx(db + j, m)];
#pragma unroll
      for (int j = 0; j < 8; ++j)
        *(unsigned*)(W1p + BIdx(m, db + 2 * j)) =
            (unsigned)tmp[2 * j] | ((unsigned)tmp[2 * j + 1] << 16);
    }
  } else {
    const unsigned short* src = ((c < 4) ? D1b : D2b) + ((c & 1) ? 128 : 0);
    const int row = tid >> 3, cb = (tid & 7) << 4;
    const unsigned short* srow = src + row * 256;
    *(uint4*)(W1p + row * 128 + cb) = *(const uint4*)(srow + cb);
    *(uint4*)(W1p + row * 128 + cb + 8) = *(const uint4*)(srow + cb + 8);
  }
}

__global__ void __launch_bounds__(NTHR, 4) dcgru(
    const float* __restrict__ inputs, const float* __restrict__ init_h,
    const float* __restrict__ sup,
    const float* __restrict__ Wg0, const float* __restrict__ bg0,
    const float* __restrict__ Wc0, const float* __restrict__ bc0,
    const float* __restrict__ Wg1, const float* __restrict__ bg1,
    const float* __restrict__ Wc1, const float* __restrict__ bc1,
    float* __restrict__ out, void* __restrict__ wsv) {
  __shared__ float Hs[16384];           // 64 KB: h state (f32, swizzled)
  __shared__ unsigned short W1[16384];  // 32 KB work tile
  __shared__ unsigned short W2[16384];  // 32 KB work tile

  unsigned* bar = (unsigned*)wsv;
  float* seqs = (float*)wsv + 64;                          // [2][16][128][128]
  float* u_ws = seqs + 524288;                             // [32][128][128]
  unsigned short* D1g = (unsigned short*)(u_ws + 524288);  // [32][128][256] bf16
  unsigned short* D2g = D1g + 1048576;
  unsigned short* Sfr = D2g + 1048576;                     // [32][8][4][64][8]
  unsigned short* Wbg = Sfr + 524288;                      // [2][16][24][64][8]
  unsigned short* Wbc = Wbg + 393216;                      // [2][8][24][64][8]

  const int tid = threadIdx.x, bid = blockIdx.x;
  const int gtid = bid * NTHR + tid, gstride = GD * NTHR;
  const int lane = tid & 63, w = tid >> 6, quad = lane >> 4, l16 = lane & 15;
  const int layer = bid >> 4, b = bid & 15;

  float* u_blk = u_ws + (long)bid * 16384;
  unsigned short* D1b = D1g + (long)bid * 32768;
  unsigned short* D2b = D2g + (long)bid * 32768;

  // ---- prep: h -> LDS; S/W fragment pre-arrangement (bf16) ----
  for (int i = tid; i < 16384; i += NTHR)
    Hs[HsIdx(i >> 7, i & 127)] = init_h[(long)(layer * 16 + b) * 16384 + i];
  for (int idx = gtid; idx < 65536; idx += gstride) {  // S frags
    const int tt = idx >> 11, mt = (idx >> 8) & 7, ks = (idx >> 6) & 3, ln = idx & 63;
    const int m = mt * 16 + (ln & 15), k0 = ks * 32 + (ln >> 4) * 8;
    const float* src = sup + (long)tt * 16384 + m * 128 + k0;
    bf16x8 v;
#pragma unroll
    for (int j = 0; j < 8; j++) v[j] = (short)f2bf(src[j]);
    *(bf16x8*)(Sfr + (long)idx * 8) = v;
  }
  for (int idx = gtid; idx < 49152; idx += gstride) {  // Wg frags (2x16x24x64)
    const int l = idx / 24576;
    int rem = idx - l * 24576;
    const int ot = rem / 1536; rem -= ot * 1536;
    const int ks = rem >> 6, ln = rem & 63;
    const int o = ot * 16 + (ln & 15);
    const float* W = l ? Wg1 : Wg0;
    bf16x8 v;
#pragma unroll
    for (int j = 0; j < 8; j++) {
      const int kk = ks * 32 + (ln >> 4) * 8 + j;
      const int mm = kk >> 8, d = kk & 255;  // row reorder (d*3+mm) -> k
      v[j] = (short)f2bf(W[(d * 3 + mm) * 256 + o]);
    }
    *(bf16x8*)(Wbg + (long)idx * 8) = v;
  }
  for (int idx = gtid; idx < 24576; idx += gstride) {  // Wc frags (2x8x24x64)
    const int l = idx / 12288;
    int rem = idx - l * 12288;
    const int ot = rem / 1536; rem -= ot * 1536;
    const int ks = rem >> 6, ln = rem & 63;
    const int o = ot * 16 + (ln & 15);
    const float* W = l ? Wc1 : Wc0;
    bf16x8 v;
#pragma unroll
    for (int j = 0; j < 8; j++) {
      const int kk = ks * 32 + (ln >> 4) * 8 + j;
      const int mm = kk >> 8, d = kk & 255;
      v[j] = (short)f2bf(W[(d * 3 + mm) * 128 + o]);
    }
    *(bf16x8*)(Wbc + (long)idx * 8) = v;
  }
  grid_barrier(bar);

  const float* bgL = layer ? bg1 : bg0;
  const float* bcL = layer ? bc1 : bc0;

  // ---- main pipelined loop: stage s, layer0 does t=s, layer1 does t=s-1 ----
  for (int s = 0; s < 33; ++s) {
    const int t = layer ? (s - 1) : s;
    const bool act = layer ? (s >= 1) : (s < 32);
    if (act) {
      const float* xsrc = (layer == 0)
          ? inputs + (long)(b * 32 + t) * 16384
          : seqs + (long)(t & 1) * 262144 + (long)b * 16384;
      const unsigned short* Sb = Sfr + (long)t * 16384;

      // ---------- P1: diffusion of cat = [x | h], two feature halves ----------
      for (int fh = 0; fh < 2; ++fh) {
        // build catT (transposed bf16) into W1
#pragma unroll
        for (int it = 0; it < 8; ++it) {
          const int f = it * 16 + (tid >> 6), n2 = (tid & 63) << 1;
          float v0, v1;
          if (fh == 0) {
            v0 = xsrc[n2 * 128 + f];
            v1 = xsrc[(n2 + 1) * 128 + f];
          } else {
            v0 = Hs[HsIdx(n2, f)];
            v1 = Hs[HsIdx(n2 + 1, f)];
          }
          *(unsigned*)(W1 + BIdx(f, n2)) = pk2(v0, v1);
        }
        __syncthreads();
        diff_half(Sb, W1, nullptr, W2, D1b, fh * 128, w, lane, quad, l16);
        __syncthreads();
        diff_half(Sb, W2, W1, nullptr, D2b, fh * 128, w, lane, quad, l16);
        __syncthreads();
      }

      // ---------- P2: gates GEMM 128x256, K=768 (8 waves, 64x64 tiles) ----------
      {
        f32x4 acc[4][4];
#pragma unroll
        for (int mi = 0; mi < 4; ++mi)
#pragma unroll
          for (int oj = 0; oj < 4; ++oj) acc[mi][oj] = (f32x4){0.f, 0.f, 0.f, 0.f};
        const int rg = w >> 2, cg = w & 3;  // valid when w < 8
        for (int c = 0; c < 6; ++c) {
          stage_chunk(c, true, tid, xsrc, Hs, W2, W1, D1b, D2b);
          __syncthreads();
          if (w < 8) {
#pragma unroll
            for (int ks = 0; ks < 4; ++ks) {
              bf16x8 a[4], bb[4];
#pragma unroll
              for (int mi = 0; mi < 4; ++mi)
                a[mi] = *(const bf16x8*)(W1 + BIdx(rg * 64 + mi * 16 + l16, ks * 32 + quad * 8));
#pragma unroll
              for (int oj = 0; oj < 4; ++oj)
                bb[oj] = *(const bf16x8*)(Wbg +
                    ((long)((layer * 16 + cg * 4 + oj) * 24 + c * 4 + ks)) * 512 + lane * 8);
#pragma unroll
              for (int mi = 0; mi < 4; ++mi)
#pragma unroll
                for (int oj = 0; oj < 4; ++oj)
                  acc[mi][oj] = __builtin_amdgcn_mfma_f32_16x16x32_bf16(
                      a[mi], bb[oj], acc[mi][oj], 0, 0, 0);
            }
          }
          __syncthreads();
        }
        if (w < 8) {
          if (cg < 2) {
            // r-gates -> rh = sigmoid(.)*h, stored TRANSPOSED (rhT) into W2
#pragma unroll
            for (int mi = 0; mi < 4; ++mi)
#pragma unroll
              for (int oj = 0; oj < 4; ++oj) {
                const int o = cg * 64 + oj * 16 + l16;
                const float bias = bgL[o];
                const int m0 = rg * 64 + mi * 16 + quad * 4;
                float rh[4];
#pragma unroll
                for (int r = 0; r < 4; ++r) {
                  const float g = 1.f / (1.f + __expf(-(acc[mi][oj][r] + bias)));
                  rh[r] = g * Hs[HsIdx(m0 + r, o)];
                }
                *(uint2*)(W2 + BIdx(o, m0)) =
                    make_uint2(pk2(rh[0], rh[1]), pk2(rh[2], rh[3]));
              }
          } else {
            // u-gates -> block-private global (read back in P4 epilogue)
#pragma unroll
            for (int mi = 0; mi < 4; ++mi)
#pragma unroll
              for (int oj = 0; oj < 4; ++oj) {
                const int og = cg * 64 + oj * 16 + l16;  // in [128,256)
                const float bias = bgL[og];
                const int m0 = rg * 64 + mi * 16 + quad * 4;
#pragma unroll
                for (int r = 0; r < 4; ++r) {
                  const float g = 1.f / (1.f + __expf(-(acc[mi][oj][r] + bias)));
                  u_blk[(m0 + r) * 128 + (og - 128)] = g;
                }
              }
          }
        }
        __syncthreads();
      }

      // ---------- P3: diffusion of rh half only ----------
      // (x-half of cat2 == x: its D1/D2 columns from P1 are reused as-is.
      //  S@rh and 2*S@(S@rh)-rh overwrite D1g/D2g columns 128..255.)
      diff_half(Sb, W2, nullptr, W1, D1b, 128, w, lane, quad, l16);
      __syncthreads();
      diff_half(Sb, W1, W2, nullptr, D2b, 128, w, lane, quad, l16);
      __syncthreads();

      // ---------- P4: candidate GEMM 128x128 (4 waves) + GRU update ----------
      {
        f32x4 acc[4][4];
#pragma unroll
        for (int mi = 0; mi < 4; ++mi)
#pragma unroll
          for (int oj = 0; oj < 4; ++oj) acc[mi][oj] = (f32x4){0.f, 0.f, 0.f, 0.f};
        const int rg = w >> 1, cg = w & 1;  // valid when w < 4
        for (int c = 0; c < 6; ++c) {
          stage_chunk(c, false, tid, xsrc, Hs, W2, W1, D1b, D2b);
          __syncthreads();
          if (w < 4) {
#pragma unroll
            for (int ks = 0; ks < 4; ++ks) {
              bf16x8 a[4], bb[4];
#pragma unroll
              for (int mi = 0; mi < 4; ++mi)
                a[mi] = *(const bf16x8*)(W1 + BIdx(rg * 64 + mi * 16 + l16, ks * 32 + quad * 8));
#pragma unroll
              for (int oj = 0; oj < 4; ++oj)
                bb[oj] = *(const bf16x8*)(Wbc +
                    ((long)((layer * 8 + cg * 4 + oj) * 24 + c * 4 + ks)) * 512 + lane * 8);
#pragma unroll
              for (int mi = 0; mi < 4; ++mi)
#pragma unroll
                for (int oj = 0; oj < 4; ++oj)
                  acc[mi][oj] = __builtin_amdgcn_mfma_f32_16x16x32_bf16(
                      a[mi], bb[oj], acc[mi][oj], 0, 0, 0);
            }
          }
          __syncthreads();
        }
        if (w < 4) {
#pragma unroll
          for (int mi = 0; mi < 4; ++mi)
#pragma unroll
            for (int oj = 0; oj < 4; ++oj) {
              const int o = cg * 64 + oj * 16 + l16;
              const float bias = bcL[o];
              const int m0 = rg * 64 + mi * 16 + quad * 4;
#pragma unroll
              for (int r = 0; r < 4; ++r) {
                const int m = m0 + r;
                const float cv = tanhf(acc[mi][oj][r] + bias);
                const float uv = u_blk[m * 128 + o];
                const float hv = Hs[HsIdx(m, o)];
                const float hn = uv * hv + (1.f - uv) * cv;
                Hs[HsIdx(m, o)] = hn;
                const long base = (long)(b * 128 + m) * 128 + o;
                if (layer == 0) {
                  seqs[(long)(s & 1) * 262144 + base] = hn;
                  if (t == 31) out[base] = hn;
                } else {
                  out[524288 + (long)t * 262144 + base] = hn;
                  if (t == 31) out[262144 + base] = hn;
                }
              }
            }
        }
      }
    }  // act
    grid_barrier(bar);
  }
}

extern "C" void kernel_launch(void* const* d_in, const int* in_sizes, int n_in,
                              void* d_out, int out_size, void* d_ws, size_t ws_size,
                              hipStream_t stream) {
  const float* inputs = (const float*)d_in[0];
  const float* init_h = (const float*)d_in[1];
  const float* sup    = (const float*)d_in[2];
  const float* Wg0 = (const float*)d_in[3];
  const float* bg0 = (const float*)d_in[4];
  const float* Wc0 = (const float*)d_in[5];
  const float* bc0 = (const float*)d_in[6];
  const float* Wg1 = (const float*)d_in[7];
  const float* bg1 = (const float*)d_in[8];
  const float* Wc1 = (const float*)d_in[9];
  const float* bc1 = (const float*)d_in[10];
  float* out = (float*)d_out;

  hipMemsetAsync(d_ws, 0, 256, stream);  // zero barrier state
  dcgru<<<GD, NTHR, 0, stream>>>(inputs, init_h, sup, Wg0, bg0, Wc0, bc0,
                                 Wg1, bg1, Wc1, bc1, out, d_ws);
}